// Round 1
// baseline (1052.907 us; speedup 1.0000x reference)
//
#include <hip/hip_runtime.h>
#include <hip/hip_bf16.h>
#include <math.h>

// Problem constants (fixed by the reference: B=4,S=2048,H=1024,D=4096)
#define H_DIM 1024
#define NBASIS 8
#define NB 9                      // 1 (silu) + 8 (spline bases)
#define K_DIM (H_DIM * NB)        // 9216
#define BT 128                    // block tile (M and O)
#define BK 64                     // K tile (bf16 elements)

typedef __bf16 bf16x8 __attribute__((ext_vector_type(8)));
typedef float f32x4 __attribute__((ext_vector_type(4)));

__device__ __forceinline__ unsigned short f2bf(float f) {
    __hip_bfloat16 h = __float2bfloat16(f);   // RNE
    return __builtin_bit_cast(unsigned short, h);
}

// ---------------------------------------------------------------------------
// Kernel 1: A[n][k] = bf16 of [silu(x), b-spline bases], k = j*H + h
// ---------------------------------------------------------------------------
__global__ void prep_a_kernel(const float* __restrict__ x,
                              unsigned short* __restrict__ A, int total) {
    int idx = blockIdx.x * 256 + threadIdx.x;
    if (idx >= total) return;
    int n = idx >> 10;            // / H_DIM
    int h = idx & (H_DIM - 1);
    float v = x[idx];

    // exact silu in fp32, like reference
    float sil = v / (1.0f + expf(-v));

    // knots: g[i] = (i-3)*0.4f + (-1.0f), i = 0..11  (matches np arange math)
    float g[12];
#pragma unroll
    for (int i = 0; i < 12; ++i) g[i] = (float)(i - 3) * 0.4f + (-1.0f);

    // Cox-de Boor, degree 0 -> 3, fp32 exactly like reference
    float b[11];
#pragma unroll
    for (int i = 0; i < 11; ++i) b[i] = (v >= g[i] && v < g[i + 1]) ? 1.0f : 0.0f;
#pragma unroll
    for (int k = 1; k <= 3; ++k) {
#pragma unroll
        for (int i = 0; i + k < 11; ++i) {
            float left  = (v - g[i]) / (g[i + k] - g[i]);
            float right = (g[i + k + 1] - v) / (g[i + k + 1] - g[i + 1]);
            b[i] = left * b[i] + right * b[i + 1];
        }
    }

    size_t base = (size_t)n * K_DIM + h;
    A[base] = f2bf(sil);
#pragma unroll
    for (int j = 0; j < NBASIS; ++j)
        A[base + (size_t)(j + 1) * H_DIM] = f2bf(b[j]);
}

// ---------------------------------------------------------------------------
// Kernel 2: B[o][k] = bf16 of [W_base, W_spline * scaler], k = j*H + h
// ---------------------------------------------------------------------------
__global__ void prep_b_kernel(const float* __restrict__ bw,
                              const float* __restrict__ sw,
                              const float* __restrict__ ss,
                              unsigned short* __restrict__ Bm, int total) {
    int idx = blockIdx.x * 256 + threadIdx.x;
    if (idx >= total) return;
    int h = idx & (H_DIM - 1);
    int o = idx >> 10;
    size_t base = (size_t)o * K_DIM + h;

    Bm[base] = f2bf(bw[idx]);
    float sc = ss[idx];
    const float4* p = (const float4*)(sw + (size_t)idx * 8);
    float4 w0 = p[0], w1 = p[1];
    Bm[base + 1 * H_DIM] = f2bf(w0.x * sc);
    Bm[base + 2 * H_DIM] = f2bf(w0.y * sc);
    Bm[base + 3 * H_DIM] = f2bf(w0.z * sc);
    Bm[base + 4 * H_DIM] = f2bf(w0.w * sc);
    Bm[base + 5 * H_DIM] = f2bf(w1.x * sc);
    Bm[base + 6 * H_DIM] = f2bf(w1.y * sc);
    Bm[base + 7 * H_DIM] = f2bf(w1.z * sc);
    Bm[base + 8 * H_DIM] = f2bf(w1.w * sc);
}

// ---------------------------------------------------------------------------
// Kernel 3: C = gelu(A @ B^T), m97-style 128x128 bf16 MFMA tile
//   A: M x K (row-major, bf16), B: D x K (row-major, bf16), out: M x D fp32
// ---------------------------------------------------------------------------
__global__ __launch_bounds__(256, 2) void gemm_kan(
    const unsigned short* __restrict__ A,
    const unsigned short* __restrict__ B,
    float* __restrict__ out, int M, int D) {

    __shared__ __align__(16) unsigned short As[BT * BK];   // 16 KB
    __shared__ __align__(16) unsigned short Bs[BT * BK];   // 16 KB

    const int tid  = threadIdx.x;
    const int lane = tid & 63;
    const int w    = tid >> 6;          // wave 0..3
    const int wr   = w >> 1, wc = w & 1;
    const int quad = lane >> 4, l16 = lane & 15;

    const int nOB  = D / BT;            // 32
    const int mBlk = blockIdx.x / nOB;
    const int oBlk = blockIdx.x % nOB;

    // --- staging addressing: chunk = w*4+t covers rows [chunk*8, chunk*8+8)
    const int baseRow = w * 32 + (lane >> 3);     // + t*8
    const int kOff    = (lane & 7) * 8;           // bf16 elements within BK
    const unsigned short* aSrc = A + (size_t)(mBlk * BT + baseRow) * K_DIM + kOff;
    const unsigned short* bSrc = B + (size_t)(oBlk * BT + baseRow) * K_DIM + kOff;
    unsigned short* aDst = &As[(w * 4) * 512];    // + t*512 (wave-uniform)
    unsigned short* bDst = &Bs[(w * 4) * 512];

    f32x4 acc[4][4];
#pragma unroll
    for (int i = 0; i < 4; ++i)
#pragma unroll
        for (int j = 0; j < 4; ++j)
            acc[i][j] = (f32x4){0.f, 0.f, 0.f, 0.f};

    for (int kt = 0; kt < K_DIM; kt += BK) {
        // global -> LDS async staging, 16 B per lane
#pragma unroll
        for (int t = 0; t < 4; ++t)
            __builtin_amdgcn_global_load_lds(
                (const __attribute__((address_space(1))) void*)(aSrc + kt + (size_t)t * 8 * K_DIM),
                (__attribute__((address_space(3))) void*)(aDst + t * 512), 16, 0, 0);
#pragma unroll
        for (int t = 0; t < 4; ++t)
            __builtin_amdgcn_global_load_lds(
                (const __attribute__((address_space(1))) void*)(bSrc + kt + (size_t)t * 8 * K_DIM),
                (__attribute__((address_space(3))) void*)(bDst + t * 512), 16, 0, 0);

        __builtin_amdgcn_s_waitcnt(0);
        __syncthreads();

#pragma unroll
        for (int kk = 0; kk < 2; ++kk) {
            bf16x8 aF[4], bF[4];
#pragma unroll
            for (int mi = 0; mi < 4; ++mi)
                aF[mi] = *reinterpret_cast<const bf16x8*>(
                    &As[(wr * 64 + mi * 16 + l16) * BK + kk * 32 + quad * 8]);
#pragma unroll
            for (int oi = 0; oi < 4; ++oi)
                bF[oi] = *reinterpret_cast<const bf16x8*>(
                    &Bs[(wc * 64 + oi * 16 + l16) * BK + kk * 32 + quad * 8]);
#pragma unroll
            for (int mi = 0; mi < 4; ++mi)
#pragma unroll
                for (int oi = 0; oi < 4; ++oi)
                    acc[mi][oi] = __builtin_amdgcn_mfma_f32_16x16x32_bf16(
                        aF[mi], bF[oi], acc[mi][oi], 0, 0, 0);
        }
        __syncthreads();
    }

    // epilogue: exact (erf) GELU, fp32 store
    const int mBase = mBlk * BT + wr * 64;
    const int oBase = oBlk * BT + wc * 64 + l16;
#pragma unroll
    for (int mi = 0; mi < 4; ++mi) {
#pragma unroll
        for (int oi = 0; oi < 4; ++oi) {
            const int o = oBase + oi * 16;
#pragma unroll
            for (int r = 0; r < 4; ++r) {
                const int m = mBase + mi * 16 + quad * 4 + r;
                float v = acc[mi][oi][r];
                float gv = 0.5f * v * (1.0f + erff(v * 0.70710678118654752f));
                out[(size_t)m * D + o] = gv;
            }
        }
    }
}

// ---------------------------------------------------------------------------
extern "C" void kernel_launch(void* const* d_in, const int* in_sizes, int n_in,
                              void* d_out, int out_size, void* d_ws, size_t ws_size,
                              hipStream_t stream) {
    const float* x  = (const float*)d_in[0];   // (B,S,H)
    const float* bw = (const float*)d_in[1];   // (D,H)
    const float* sw = (const float*)d_in[2];   // (D,H,8)
    const float* ss = (const float*)d_in[3];   // (D,H)
    float* out = (float*)d_out;

    const int M = in_sizes[0] / H_DIM;         // 8192
    const int D = in_sizes[1] / H_DIM;         // 4096

    unsigned short* Aws = (unsigned short*)d_ws;              // M x K bf16
    unsigned short* Bws = Aws + (size_t)M * K_DIM;            // D x K bf16

    const int totA = M * H_DIM;
    prep_a_kernel<<<(totA + 255) / 256, 256, 0, stream>>>(x, Aws, totA);
    const int totB = D * H_DIM;
    prep_b_kernel<<<(totB + 255) / 256, 256, 0, stream>>>(bw, sw, ss, Bws, totB);

    dim3 grid((M / BT) * (D / BT));            // 64*32 = 2048 blocks
    gemm_kan<<<grid, 256, 0, stream>>>(Aws, Bws, out, M, D);
}

// Round 2
// 962.052 us; speedup vs baseline: 1.0944x; 1.0944x over previous
//
#include <hip/hip_runtime.h>
#include <hip/hip_bf16.h>
#include <math.h>

// Problem constants (fixed by the reference: B=4,S=2048,H=1024,D=4096)
#define H_DIM 1024
#define NBASIS 8
#define NB 9                      // 1 (silu) + 8 (spline bases)
#define K_DIM (H_DIM * NB)        // 9216
#define BT 128                    // block tile (M and O)
#define BK 64                     // K tile (bf16 elements)

typedef __bf16 bf16x8 __attribute__((ext_vector_type(8)));
typedef float f32x4 __attribute__((ext_vector_type(4)));
typedef unsigned short u16x8 __attribute__((ext_vector_type(8)));

__device__ __forceinline__ unsigned short f2bf(float f) {
    __hip_bfloat16 h = __float2bfloat16(f);   // RNE
    return __builtin_bit_cast(unsigned short, h);
}

// ---------------------------------------------------------------------------
// Kernel 1: A[n][k] = bf16 of [silu(x), b-spline bases], k = j*H + h
// Each thread handles 8 consecutive h -> 9 x 16B vector stores.
// ---------------------------------------------------------------------------
__global__ void prep_a_kernel(const float* __restrict__ x,
                              unsigned short* __restrict__ A, int totalVec) {
    int idx = blockIdx.x * 256 + threadIdx.x;
    if (idx >= totalVec) return;
    int n  = idx >> 7;                  // H/8 = 128 vecs per row
    int h0 = (idx & 127) * 8;

    const float4* xp = (const float4*)(x + (size_t)n * H_DIM + h0);
    float4 v0 = xp[0], v1 = xp[1];
    float xv[8] = {v0.x, v0.y, v0.z, v0.w, v1.x, v1.y, v1.z, v1.w};

    u16x8 outv[9];
#pragma unroll
    for (int e = 0; e < 8; ++e) {
        float v = xv[e];
        float sil = v / (1.0f + expf(-v));
        outv[0][e] = f2bf(sil);

        // Cox-de Boor cubic, knots g[i] = (i-3)*0.4f - 1.0f (fp32, as reference)
        float b[11];
#pragma unroll
        for (int i = 0; i < 11; ++i) {
            const float gi  = (float)(i - 3) * 0.4f + (-1.0f);
            const float gi1 = (float)(i - 2) * 0.4f + (-1.0f);
            b[i] = (v >= gi && v < gi1) ? 1.0f : 0.0f;
        }
#pragma unroll
        for (int k = 1; k <= 3; ++k) {
#pragma unroll
            for (int i = 0; i + k < 11; ++i) {
                const float gi   = (float)(i - 3) * 0.4f + (-1.0f);
                const float gi1  = (float)(i - 2) * 0.4f + (-1.0f);
                const float gik  = (float)(i + k - 3) * 0.4f + (-1.0f);
                const float gik1 = (float)(i + k - 2) * 0.4f + (-1.0f);
                float left  = (v - gi)   * (1.0f / (gik - gi));    // consts fold
                float right = (gik1 - v) * (1.0f / (gik1 - gi1));
                b[i] = left * b[i] + right * b[i + 1];
            }
        }
#pragma unroll
        for (int j = 0; j < NBASIS; ++j) outv[j + 1][e] = f2bf(b[j]);
    }

    size_t base = (size_t)n * K_DIM + h0;
#pragma unroll
    for (int j = 0; j < NB; ++j)
        *reinterpret_cast<u16x8*>(A + base + (size_t)j * H_DIM) = outv[j];
}

// ---------------------------------------------------------------------------
// Kernel 2: B[o][k] = bf16 of [W_base, W_spline * scaler], k = j*H + h
// Each thread handles 8 consecutive (o,h) elements -> 9 x 16B vector stores.
// ---------------------------------------------------------------------------
__global__ void prep_b_kernel(const float* __restrict__ bw,
                              const float* __restrict__ sw,
                              const float* __restrict__ ss,
                              unsigned short* __restrict__ Bm, int totalVec) {
    int idx = blockIdx.x * 256 + threadIdx.x;
    if (idx >= totalVec) return;
    int o  = idx >> 7;
    int h0 = (idx & 127) * 8;
    size_t ib = (size_t)o * H_DIM + h0;

    float4 b0 = *(const float4*)(bw + ib);
    float4 b1 = *(const float4*)(bw + ib + 4);
    float4 s0 = *(const float4*)(ss + ib);
    float4 s1 = *(const float4*)(ss + ib + 4);
    float bwv[8] = {b0.x, b0.y, b0.z, b0.w, b1.x, b1.y, b1.z, b1.w};
    float scv[8] = {s0.x, s0.y, s0.z, s0.w, s1.x, s1.y, s1.z, s1.w};

    float w[8][8];
#pragma unroll
    for (int e = 0; e < 8; ++e) {
        const float4* p = (const float4*)(sw + (ib + e) * 8);
        float4 w0 = p[0], w1 = p[1];
        w[e][0] = w0.x; w[e][1] = w0.y; w[e][2] = w0.z; w[e][3] = w0.w;
        w[e][4] = w1.x; w[e][5] = w1.y; w[e][6] = w1.z; w[e][7] = w1.w;
    }

    size_t base = (size_t)o * K_DIM + h0;
    u16x8 vb;
#pragma unroll
    for (int e = 0; e < 8; ++e) vb[e] = f2bf(bwv[e]);
    *reinterpret_cast<u16x8*>(Bm + base) = vb;
#pragma unroll
    for (int j = 0; j < NBASIS; ++j) {
        u16x8 vj;
#pragma unroll
        for (int e = 0; e < 8; ++e) vj[e] = f2bf(w[e][j] * scv[e]);
        *reinterpret_cast<u16x8*>(Bm + base + (size_t)(j + 1) * H_DIM) = vj;
    }
}

// ---------------------------------------------------------------------------
// Kernel 3: C = gelu(A @ B^T), 128x128 bf16 MFMA tile with XOR-swizzled LDS
//   A: M x K (row-major, bf16), B: D x K (row-major, bf16), out: M x D fp32
//   LDS[r][c] holds global chunk c ^ (r&7) of row r (16B chunks) -> fragment
//   reads spread over all 32 banks (8 lanes per 4-bank group = conflict-free).
// ---------------------------------------------------------------------------
__global__ __launch_bounds__(256, 4) void gemm_kan(
    const unsigned short* __restrict__ A,
    const unsigned short* __restrict__ B,
    float* __restrict__ out, int M, int D) {

    __shared__ __align__(16) unsigned short As[BT * BK];   // 16 KB
    __shared__ __align__(16) unsigned short Bs[BT * BK];   // 16 KB

    const int tid  = threadIdx.x;
    const int lane = tid & 63;
    const int w    = tid >> 6;          // wave 0..3
    const int wr   = w >> 1, wc = w & 1;
    const int quad = lane >> 4, l16 = lane & 15;

    const int nOB  = D / BT;            // 32
    const int mBlk = blockIdx.x / nOB;
    const int oBlk = blockIdx.x % nOB;

    // --- staging: chunk t of wave w covers rows [w*32+t*8, +8)
    // lane l -> row +(l>>3); global source chunk is XOR-swizzled by row&7
    const int baseRow = w * 32 + (lane >> 3);
    const int kOff    = (((lane & 7) ^ (lane >> 3)) * 8);   // swizzled source
    const unsigned short* aSrc = A + (size_t)(mBlk * BT + baseRow) * K_DIM + kOff;
    const unsigned short* bSrc = B + (size_t)(oBlk * BT + baseRow) * K_DIM + kOff;
    unsigned short* aDst = &As[(w * 4) * 512];    // + t*512 (wave-uniform)
    unsigned short* bDst = &Bs[(w * 4) * 512];

    f32x4 acc[4][4];
#pragma unroll
    for (int i = 0; i < 4; ++i)
#pragma unroll
        for (int j = 0; j < 4; ++j)
            acc[i][j] = (f32x4){0.f, 0.f, 0.f, 0.f};

    for (int kt = 0; kt < K_DIM; kt += BK) {
#pragma unroll
        for (int t = 0; t < 4; ++t)
            __builtin_amdgcn_global_load_lds(
                (const __attribute__((address_space(1))) void*)(aSrc + kt + (size_t)t * 8 * K_DIM),
                (__attribute__((address_space(3))) void*)(aDst + t * 512), 16, 0, 0);
#pragma unroll
        for (int t = 0; t < 4; ++t)
            __builtin_amdgcn_global_load_lds(
                (const __attribute__((address_space(1))) void*)(bSrc + kt + (size_t)t * 8 * K_DIM),
                (__attribute__((address_space(3))) void*)(bDst + t * 512), 16, 0, 0);

        __builtin_amdgcn_s_waitcnt(0);
        __syncthreads();

#pragma unroll
        for (int kk = 0; kk < 2; ++kk) {
            // swizzled chunk select: chunk' = (kk*4+quad) ^ (l16&7)
            const int csel = (((kk * 4 + quad) ^ (l16 & 7)) * 8);
            bf16x8 aF[4], bF[4];
#pragma unroll
            for (int mi = 0; mi < 4; ++mi)
                aF[mi] = *reinterpret_cast<const bf16x8*>(
                    &As[(wr * 64 + mi * 16 + l16) * BK + csel]);
#pragma unroll
            for (int oi = 0; oi < 4; ++oi)
                bF[oi] = *reinterpret_cast<const bf16x8*>(
                    &Bs[(wc * 64 + oi * 16 + l16) * BK + csel]);
#pragma unroll
            for (int mi = 0; mi < 4; ++mi)
#pragma unroll
                for (int oi = 0; oi < 4; ++oi)
                    acc[mi][oi] = __builtin_amdgcn_mfma_f32_16x16x32_bf16(
                        aF[mi], bF[oi], acc[mi][oi], 0, 0, 0);
        }
        __syncthreads();
    }

    // epilogue: exact (erf) GELU, fp32 store
    const int mBase = mBlk * BT + wr * 64;
    const int oBase = oBlk * BT + wc * 64 + l16;
#pragma unroll
    for (int mi = 0; mi < 4; ++mi) {
#pragma unroll
        for (int oi = 0; oi < 4; ++oi) {
            const int o = oBase + oi * 16;
#pragma unroll
            for (int r = 0; r < 4; ++r) {
                const int m = mBase + mi * 16 + quad * 4 + r;
                float v = acc[mi][oi][r];
                float gv = 0.5f * v * (1.0f + erff(v * 0.70710678118654752f));
                out[(size_t)m * D + o] = gv;
            }
        }
    }
}

// ---------------------------------------------------------------------------
extern "C" void kernel_launch(void* const* d_in, const int* in_sizes, int n_in,
                              void* d_out, int out_size, void* d_ws, size_t ws_size,
                              hipStream_t stream) {
    const float* x  = (const float*)d_in[0];   // (B,S,H)
    const float* bw = (const float*)d_in[1];   // (D,H)
    const float* sw = (const float*)d_in[2];   // (D,H,8)
    const float* ss = (const float*)d_in[3];   // (D,H)
    float* out = (float*)d_out;

    const int M = in_sizes[0] / H_DIM;         // 8192
    const int D = in_sizes[1] / H_DIM;         // 4096

    unsigned short* Aws = (unsigned short*)d_ws;              // M x K bf16
    unsigned short* Bws = Aws + (size_t)M * K_DIM;            // D x K bf16

    const int totAv = M * H_DIM / 8;
    prep_a_kernel<<<(totAv + 255) / 256, 256, 0, stream>>>(x, Aws, totAv);
    const int totBv = D * H_DIM / 8;
    prep_b_kernel<<<(totBv + 255) / 256, 256, 0, stream>>>(bw, sw, ss, Bws, totBv);

    dim3 grid((M / BT) * (D / BT));            // 64*32 = 2048 blocks
    gemm_kan<<<grid, 256, 0, stream>>>(Aws, Bws, out, M, D);
}

// Round 3
// 950.602 us; speedup vs baseline: 1.1076x; 1.0120x over previous
//
#include <hip/hip_runtime.h>
#include <hip/hip_bf16.h>
#include <math.h>

// Problem constants (fixed by the reference: B=4,S=2048,H=1024,D=4096)
#define H_DIM 1024
#define NBASIS 8
#define K_DIM 9216                // 8*H (spline, k=h*8+j) + H (silu, k=8192+h)
#define K_SILU 8192
#define BT 128                    // block tile (M and O)
#define BK 64                     // K tile (bf16 elements)

typedef __bf16 bf16x8 __attribute__((ext_vector_type(8)));
typedef float f32x4 __attribute__((ext_vector_type(4)));
typedef unsigned short u16x8 __attribute__((ext_vector_type(8)));

__device__ __forceinline__ unsigned short f2bf(float f) {
    __hip_bfloat16 h = __float2bfloat16(f);   // RNE
    return __builtin_bit_cast(unsigned short, h);
}

// ---------------------------------------------------------------------------
// Kernel 1: A[n][h*8+j] = bf16 bases, A[n][8192+h] = bf16 silu(x)
// Thread per (n,h): 4B read, 16B + 2B contiguous writes. Fully coalesced.
// ---------------------------------------------------------------------------
__global__ void prep_a_kernel(const float* __restrict__ x,
                              unsigned short* __restrict__ A, int total) {
    int idx = blockIdx.x * 256 + threadIdx.x;   // idx = n*H + h
    if (idx >= total) return;
    int n = idx >> 10;
    int h = idx & (H_DIM - 1);
    float v = x[idx];

    float sil = v / (1.0f + __expf(-v));

    // Cox-de Boor cubic, knots g[i] = (i-3)*0.4f - 1.0f (fp32, as reference)
    float b[11];
#pragma unroll
    for (int i = 0; i < 11; ++i) {
        const float gi  = (float)(i - 3) * 0.4f + (-1.0f);
        const float gi1 = (float)(i - 2) * 0.4f + (-1.0f);
        b[i] = (v >= gi && v < gi1) ? 1.0f : 0.0f;
    }
#pragma unroll
    for (int k = 1; k <= 3; ++k) {
#pragma unroll
        for (int i = 0; i + k < 11; ++i) {
            const float gi   = (float)(i - 3) * 0.4f + (-1.0f);
            const float gi1  = (float)(i - 2) * 0.4f + (-1.0f);
            const float gik  = (float)(i + k - 3) * 0.4f + (-1.0f);
            const float gik1 = (float)(i + k - 2) * 0.4f + (-1.0f);
            float left  = (v - gi)   * (1.0f / (gik - gi));    // consts fold
            float right = (gik1 - v) * (1.0f / (gik1 - gi1));
            b[i] = left * b[i] + right * b[i + 1];
        }
    }

    u16x8 pack;
#pragma unroll
    for (int j = 0; j < NBASIS; ++j) pack[j] = f2bf(b[j]);

    size_t rowBase = (size_t)n * K_DIM;
    *reinterpret_cast<u16x8*>(A + rowBase + (size_t)h * 8) = pack;
    A[rowBase + K_SILU + h] = f2bf(sil);
}

// ---------------------------------------------------------------------------
// Kernel 2: B[o][h*8+j] = bf16(sw*scaler), B[o][8192+h] = bf16(bw)
// Thread per (o,h): 32B+4B+4B reads, 16B + 2B writes. Fully coalesced.
// ---------------------------------------------------------------------------
__global__ void prep_b_kernel(const float* __restrict__ bw,
                              const float* __restrict__ sw,
                              const float* __restrict__ ss,
                              unsigned short* __restrict__ Bm, int total) {
    int idx = blockIdx.x * 256 + threadIdx.x;   // idx = o*H + h
    if (idx >= total) return;
    int o = idx >> 10;
    int h = idx & (H_DIM - 1);

    const float4* p = (const float4*)(sw + (size_t)idx * 8);
    float4 w0 = p[0], w1 = p[1];
    float sc = ss[idx];

    u16x8 pack;
    pack[0] = f2bf(w0.x * sc); pack[1] = f2bf(w0.y * sc);
    pack[2] = f2bf(w0.z * sc); pack[3] = f2bf(w0.w * sc);
    pack[4] = f2bf(w1.x * sc); pack[5] = f2bf(w1.y * sc);
    pack[6] = f2bf(w1.z * sc); pack[7] = f2bf(w1.w * sc);

    size_t rowBase = (size_t)o * K_DIM;
    *reinterpret_cast<u16x8*>(Bm + rowBase + (size_t)h * 8) = pack;
    Bm[rowBase + K_SILU + h] = f2bf(bw[idx]);
}

// ---------------------------------------------------------------------------
// Kernel 3: C = gelu(A @ B^T), 128x128 bf16 MFMA tile with XOR-swizzled LDS
//   A: M x K (row-major, bf16), B: D x K (row-major, bf16), out: M x D fp32
//   (unchanged from round 2 — K-layout-invariant; 0 bank conflicts measured)
// ---------------------------------------------------------------------------
__global__ __launch_bounds__(256, 4) void gemm_kan(
    const unsigned short* __restrict__ A,
    const unsigned short* __restrict__ B,
    float* __restrict__ out, int M, int D) {

    __shared__ __align__(16) unsigned short As[BT * BK];   // 16 KB
    __shared__ __align__(16) unsigned short Bs[BT * BK];   // 16 KB

    const int tid  = threadIdx.x;
    const int lane = tid & 63;
    const int w    = tid >> 6;          // wave 0..3
    const int wr   = w >> 1, wc = w & 1;
    const int quad = lane >> 4, l16 = lane & 15;

    const int nOB  = D / BT;            // 32
    const int mBlk = blockIdx.x / nOB;
    const int oBlk = blockIdx.x % nOB;

    // --- staging: chunk t of wave w covers rows [w*32+t*8, +8)
    // lane l -> row +(l>>3); global source chunk is XOR-swizzled by row&7
    const int baseRow = w * 32 + (lane >> 3);
    const int kOff    = (((lane & 7) ^ (lane >> 3)) * 8);   // swizzled source
    const unsigned short* aSrc = A + (size_t)(mBlk * BT + baseRow) * K_DIM + kOff;
    const unsigned short* bSrc = B + (size_t)(oBlk * BT + baseRow) * K_DIM + kOff;
    unsigned short* aDst = &As[(w * 4) * 512];    // + t*512 (wave-uniform)
    unsigned short* bDst = &Bs[(w * 4) * 512];

    f32x4 acc[4][4];
#pragma unroll
    for (int i = 0; i < 4; ++i)
#pragma unroll
        for (int j = 0; j < 4; ++j)
            acc[i][j] = (f32x4){0.f, 0.f, 0.f, 0.f};

    for (int kt = 0; kt < K_DIM; kt += BK) {
#pragma unroll
        for (int t = 0; t < 4; ++t)
            __builtin_amdgcn_global_load_lds(
                (const __attribute__((address_space(1))) void*)(aSrc + kt + (size_t)t * 8 * K_DIM),
                (__attribute__((address_space(3))) void*)(aDst + t * 512), 16, 0, 0);
#pragma unroll
        for (int t = 0; t < 4; ++t)
            __builtin_amdgcn_global_load_lds(
                (const __attribute__((address_space(1))) void*)(bSrc + kt + (size_t)t * 8 * K_DIM),
                (__attribute__((address_space(3))) void*)(bDst + t * 512), 16, 0, 0);

        __builtin_amdgcn_s_waitcnt(0);
        __syncthreads();

#pragma unroll
        for (int kk = 0; kk < 2; ++kk) {
            // swizzled chunk select: chunk' = (kk*4+quad) ^ (l16&7)
            const int csel = (((kk * 4 + quad) ^ (l16 & 7)) * 8);
            bf16x8 aF[4], bF[4];
#pragma unroll
            for (int mi = 0; mi < 4; ++mi)
                aF[mi] = *reinterpret_cast<const bf16x8*>(
                    &As[(wr * 64 + mi * 16 + l16) * BK + csel]);
#pragma unroll
            for (int oi = 0; oi < 4; ++oi)
                bF[oi] = *reinterpret_cast<const bf16x8*>(
                    &Bs[(wc * 64 + oi * 16 + l16) * BK + csel]);
#pragma unroll
            for (int mi = 0; mi < 4; ++mi)
#pragma unroll
                for (int oi = 0; oi < 4; ++oi)
                    acc[mi][oi] = __builtin_amdgcn_mfma_f32_16x16x32_bf16(
                        aF[mi], bF[oi], acc[mi][oi], 0, 0, 0);
        }
        __syncthreads();
    }

    // epilogue: exact (erf) GELU, fp32 store
    const int mBase = mBlk * BT + wr * 64;
    const int oBase = oBlk * BT + wc * 64 + l16;
#pragma unroll
    for (int mi = 0; mi < 4; ++mi) {
#pragma unroll
        for (int oi = 0; oi < 4; ++oi) {
            const int o = oBase + oi * 16;
#pragma unroll
            for (int r = 0; r < 4; ++r) {
                const int m = mBase + mi * 16 + quad * 4 + r;
                float v = acc[mi][oi][r];
                float gv = 0.5f * v * (1.0f + erff(v * 0.70710678118654752f));
                out[(size_t)m * D + o] = gv;
            }
        }
    }
}

// ---------------------------------------------------------------------------
extern "C" void kernel_launch(void* const* d_in, const int* in_sizes, int n_in,
                              void* d_out, int out_size, void* d_ws, size_t ws_size,
                              hipStream_t stream) {
    const float* x  = (const float*)d_in[0];   // (B,S,H)
    const float* bw = (const float*)d_in[1];   // (D,H)
    const float* sw = (const float*)d_in[2];   // (D,H,8)
    const float* ss = (const float*)d_in[3];   // (D,H)
    float* out = (float*)d_out;

    const int M = in_sizes[0] / H_DIM;         // 8192
    const int D = in_sizes[1] / H_DIM;         // 4096

    unsigned short* Aws = (unsigned short*)d_ws;              // M x K bf16
    unsigned short* Bws = Aws + (size_t)M * K_DIM;            // D x K bf16

    const int totA = M * H_DIM;
    prep_a_kernel<<<(totA + 255) / 256, 256, 0, stream>>>(x, Aws, totA);
    const int totB = D * H_DIM;
    prep_b_kernel<<<(totB + 255) / 256, 256, 0, stream>>>(bw, sw, ss, Bws, totB);

    dim3 grid((M / BT) * (D / BT));            // 64*32 = 2048 blocks
    gemm_kan<<<grid, 256, 0, stream>>>(Aws, Bws, out, M, D);
}